// Round 1
// 3619.662 us; speedup vs baseline: 1.2404x; 1.2404x over previous
//
#include <hip/hip_runtime.h>
#include <hip/hip_fp16.h>

typedef _Float16 half8 __attribute__((ext_vector_type(8)));
typedef _Float16 half4v __attribute__((ext_vector_type(4)));
typedef float floatx4 __attribute__((ext_vector_type(4)));

constexpr int BN = 128;    // batch
constexpr int T  = 1024;   // time steps
constexpr int D  = 512;    // input dim
constexpr int H  = 512;    // hidden dim

// Workspace layout (bytes)
constexpr size_t OFF_WIHT  = 0;                    // W_ih^T f16 = 512 KB
constexpr size_t OFF_WHHT  = 524288;               // W_hh^T f16 = 512 KB
constexpr size_t OFF_HX    = 1048576;              // h exchange: 2*8*2*4096 f16 = 256 KB
constexpr size_t OFF_FLAGS = 1048576 + 262144;     // 16 flags, 64B stride = 1 KB
constexpr size_t OFF_XP    = 2097152;              // xp f16 [T][B][H] = 128 MB

__device__ __forceinline__ float fast_tanh(float x) {
    float e = __expf(2.0f * x);
    return 1.0f - 2.0f / (e + 1.0f);
}

// ---------------------------------------------------------------------------
// Prep: transpose 512x512 fp32 -> fp16 (row-major [n][k] = W[k][n]).
// Also re-zeroes the scan handshake flags every launch (stream order
// guarantees completion+visibility before rnn_scan starts).
// ---------------------------------------------------------------------------
__global__ __launch_bounds__(256) void prep_transpose(
    const float* __restrict__ Wih, const float* __restrict__ Whh,
    _Float16* __restrict__ WihT, _Float16* __restrict__ WhhT,
    int* __restrict__ flags)
{
    if (blockIdx.x == 0 && blockIdx.y == 0 && blockIdx.z == 0 && threadIdx.x < 16)
        flags[threadIdx.x * 16] = 0;

    __shared__ float tile[32][33];
    const float* src = (blockIdx.z == 0) ? Wih : Whh;
    _Float16* dst    = (blockIdx.z == 0) ? WihT : WhhT;
    const int tx = threadIdx.x & 31;
    const int ty = threadIdx.x >> 5;
    const int kbase = blockIdx.y * 32;
    const int nbase = blockIdx.x * 32;
    for (int r = 0; r < 4; ++r)
        tile[ty + r * 8][tx] = src[(size_t)(kbase + ty + r * 8) * 512 + nbase + tx];
    __syncthreads();
    for (int r = 0; r < 4; ++r)
        dst[(size_t)(nbase + ty + r * 8) * 512 + kbase + tx] =
            (_Float16)tile[tx][ty + r * 8];
}

// ---------------------------------------------------------------------------
// Phase 1: xp[t][b][n] = x[b][t][:] @ W_ih + bias   (fp16 out, bias folded)
// ---------------------------------------------------------------------------
__global__ __launch_bounds__(256) void xp_gemm(
    const float* __restrict__ x, const _Float16* __restrict__ WT,
    const float* __restrict__ bias, _Float16* __restrict__ xp)
{
    __shared__ _Float16 As[128][40];
    __shared__ _Float16 Bs[128][40];
    const int tid  = threadIdx.x;
    const int lane = tid & 63;
    const int w    = tid >> 6;
    const int wm   = w & 1, wn = w >> 1;
    const int l15  = lane & 15, q = lane >> 4;
    const size_t mbase = (size_t)blockIdx.y * 128;
    const int    nbase = blockIdx.x * 128;

    floatx4 acc[4][4];
    for (int i = 0; i < 4; ++i)
        for (int j = 0; j < 4; ++j)
            acc[i][j] = (floatx4){0.f, 0.f, 0.f, 0.f};

    for (int kt = 0; kt < 16; ++kt) {
        const int k0 = kt * 32;
        {
            const int k4 = (tid & 7) * 4;
            const int row0 = tid >> 3;
            for (int r = 0; r < 4; ++r) {
                const int row = row0 + r * 32;
                const float4 v = *(const float4*)&x[(mbase + row) * D + k0 + k4];
                half4v hv;
                hv[0] = (_Float16)v.x; hv[1] = (_Float16)v.y;
                hv[2] = (_Float16)v.z; hv[3] = (_Float16)v.w;
                *(half4v*)&As[row][k4] = hv;
            }
        }
        {
            const int k8 = (tid & 3) * 8;
            const int n0 = tid >> 2;
            for (int r = 0; r < 2; ++r) {
                const int n = n0 + r * 64;
                *(half8*)&Bs[n][k8] =
                    *(const half8*)&WT[(size_t)(nbase + n) * D + k0 + k8];
            }
        }
        __syncthreads();
        half8 a[4], b[4];
        for (int i = 0; i < 4; ++i)
            a[i] = *(const half8*)&As[wm * 64 + i * 16 + l15][q * 8];
        for (int j = 0; j < 4; ++j)
            b[j] = *(const half8*)&Bs[wn * 64 + j * 16 + l15][q * 8];
        for (int i = 0; i < 4; ++i)
            for (int j = 0; j < 4; ++j)
                acc[i][j] = __builtin_amdgcn_mfma_f32_16x16x32_f16(
                    a[i], b[j], acc[i][j], 0, 0, 0);
        __syncthreads();
    }
    float bc[4];
    for (int j = 0; j < 4; ++j)
        bc[j] = bias[nbase + wn * 64 + j * 16 + l15];
    for (int i = 0; i < 4; ++i)
        for (int r = 0; r < 4; ++r) {
            const size_t row = mbase + wm * 64 + i * 16 + q * 4 + r;
            const int b_row = (int)(row >> 10);      // T = 1024
            const int tt    = (int)(row & 1023);
            _Float16* dst = &xp[((size_t)tt * BN + b_row) * H];
            for (int j = 0; j < 4; ++j) {
                const int col = nbase + wn * 64 + j * 16 + l15;
                dst[col] = (_Float16)(acc[i][j][r] + bc[j]);
            }
        }
}

// ---------------------------------------------------------------------------
// Phase 2: sequential scan, H-split across 16 CUs.
// Block (g, half): 16 batch rows (group g), 256 output cols [half*256, ...).
// The block's 256KB W_hh^T slice lives ENTIRELY in AGPRs (8 waves x 128):
// no LDS W banks, no L2 streaming, ~100 arch VGPRs freed for the scheduler.
// Per step the peer block's 256-col half of h is exchanged through an
// L3-resident buffer with agent-scope atomics (bypasses the non-coherent
// per-XCD L2s) + release/acquire flag. Own-half MFMAs run first so the
// exchange latency overlaps compute. Blocks pairwise self-lockstep (each is
// <=1 step ahead of its peer), parity double-buffer prevents overwrite.
// wa[] is ordered own-chunks-first so all register indices are compile-time.
// ---------------------------------------------------------------------------
__global__ __launch_bounds__(512, 2) void rnn_scan(
    const _Float16* __restrict__ xp, const _Float16* __restrict__ WT,
    float* __restrict__ out, _Float16* __restrict__ hx, int* __restrict__ flags)
{
    __shared__ _Float16 hbuf[2][16 * 512];   // 32 KB, fragment-permuted full h

    const int bid  = blockIdx.x;        // 0..15
    const int half = bid >> 3;          // output column half
    const int g    = bid & 7;           // batch group
    const int peer = bid ^ 8;           // partner block (other half, same g)
    const int tid  = threadIdx.x;
    const int lane = tid & 63;
    const int w    = tid >> 6;          // wave 0..7
    const int l15  = lane & 15;
    const int q    = lane >> 4;

    const int hoff = half * 4096;       // own fragment region (f16 elems)
    const int poff = hoff ^ 4096;       // peer fragment region

    // W^T rows for this wave's two 16-row m-tiles
    const int nbase = half * 256 + w * 32;
    const _Float16* wr0 = WT + (size_t)(nbase + 0  + l15) * H + q * 8;
    const _Float16* wr1 = WT + (size_t)(nbase + 16 + l15) * H + q * 8;

    // Whole W slice in AGPRs: j=0..7 own-half k-chunks, j=8..15 peer-half
    half8 wa[16][2];
#pragma unroll
    for (int j = 0; j < 16; ++j) {
        const int c = (j < 8) ? (half * 8 + j) : ((half ^ 1) * 8 + (j - 8));
        wa[j][0] = *(const half8*)&wr0[c * 32];
        wa[j][1] = *(const half8*)&wr1[c * 32];
        asm volatile("" : "+a"(wa[j][0]), "+a"(wa[j][1]));
    }

    // ---- t = 0: h1 = tanh(xp_0), full 512-wide, computed locally
    {
        const _Float16* x0 = xp + ((size_t)g * 16 + l15) * H;
#pragma unroll
        for (int i = 0; i < 4; ++i) {
            const int hid = w * 64 + i * 16 + q * 4;
            half4v v = *(const half4v*)&x0[hid];
            half4v hn;
#pragma unroll
            for (int r = 0; r < 4; ++r)
                hn[r] = (_Float16)fast_tanh((float)v[r]);
            const int c = hid >> 5, qr = (hid >> 3) & 3, lo = hid & 7;
            *(half4v*)&hbuf[1][((c * 4 + qr) * 16 + l15) * 8 + lo] = hn;
        }
        __syncthreads();
    }

    // lane-fixed xp offset (own 32 cols); own fragment write base (hx-relative)
    const _Float16* xlane = xp + ((size_t)g * 16 + l15) * H + nbase + q * 4;
    const int ebase = (w * 4 + (q >> 1)) * 128 + l15 * 8 + (q & 1) * 4;

    for (int t = 1; t < T; ++t) {
        const _Float16* hb = hbuf[t & 1];

        // xp prefetch (independent of h)
        const _Float16* xt = xlane + (size_t)t * (BN * H);
        const half4v xpv0 = *(const half4v*)&xt[0];
        const half4v xpv1 = *(const half4v*)&xt[16];

        // early relaxed flag probe (overlaps phase 1; no ordering cost)
        int f = 0x7fffffff;
        if (t >= 2 && lane == 0)
            f = __hip_atomic_load(&flags[peer * 16], __ATOMIC_RELAXED,
                                  __HIP_MEMORY_SCOPE_AGENT);

        // ---- phase 1: own-half k-chunks (data already local in LDS)
        const _Float16* hbo = hb + hoff + (q * 16 + l15) * 8;
        half8 hfA[8];
#pragma unroll
        for (int c8 = 0; c8 < 8; ++c8)
            hfA[c8] = *(const half8*)&hbo[c8 * 512];
        floatx4 accA0 = (floatx4){0.f,0.f,0.f,0.f};
        floatx4 accA1 = (floatx4){0.f,0.f,0.f,0.f};
#pragma unroll
        for (int c8 = 0; c8 < 8; ++c8) {
            accA0 = __builtin_amdgcn_mfma_f32_16x16x32_f16(wa[c8][0], hfA[c8], accA0, 0, 0, 0);
            accA1 = __builtin_amdgcn_mfma_f32_16x16x32_f16(wa[c8][1], hfA[c8], accA1, 0, 0, 0);
        }

        // ---- exchange-in: peer half of h_t (t==1: already local from init)
        if (t >= 2) {
            if (lane == 0) {
                while (f < t - 1) {
                    __builtin_amdgcn_s_sleep(1);
                    f = __hip_atomic_load(&flags[peer * 16], __ATOMIC_ACQUIRE,
                                          __HIP_MEMORY_SCOPE_AGENT);
                }
            }
            // flag value returned >= t-1 before these issue (branch depends on
            // it); producer's release drained its data stores to L3 first.
            const size_t sb = ((size_t)((t & 1) * 8 + g) * 2 + (half ^ 1)) * 4096;
            unsigned long long* src = (unsigned long long*)(hx + sb);
            unsigned long long d0 = __hip_atomic_load(&src[tid * 2 + 0],
                                    __ATOMIC_RELAXED, __HIP_MEMORY_SCOPE_AGENT);
            unsigned long long d1 = __hip_atomic_load(&src[tid * 2 + 1],
                                    __ATOMIC_RELAXED, __HIP_MEMORY_SCOPE_AGENT);
            unsigned long long* dl = (unsigned long long*)&hbuf[t & 1][poff];
            dl[tid * 2 + 0] = d0;
            dl[tid * 2 + 1] = d1;
            __syncthreads();
        }

        // ---- phase 2: peer-half k-chunks
        const _Float16* hbp = hb + poff + (q * 16 + l15) * 8;
        half8 hfB[8];
#pragma unroll
        for (int c8 = 0; c8 < 8; ++c8)
            hfB[c8] = *(const half8*)&hbp[c8 * 512];
        floatx4 accB0 = (floatx4){0.f,0.f,0.f,0.f};
        floatx4 accB1 = (floatx4){0.f,0.f,0.f,0.f};
#pragma unroll
        for (int c8 = 0; c8 < 8; ++c8) {
            accB0 = __builtin_amdgcn_mfma_f32_16x16x32_f16(wa[8 + c8][0], hfB[c8], accB0, 0, 0, 0);
            accB1 = __builtin_amdgcn_mfma_f32_16x16x32_f16(wa[8 + c8][1], hfB[c8], accB1, 0, 0, 0);
        }

        const floatx4 acc0 = accA0 + accB0;
        const floatx4 acc1 = accA1 + accB1;

        if (t < T - 1) {
            _Float16* ho  = hbuf[(t + 1) & 1];
            _Float16* hxo = hx + ((size_t)(((t + 1) & 1) * 8 + g) * 2 + half) * 4096;
            half4v hn0, hn1;
#pragma unroll
            for (int r = 0; r < 4; ++r) {
                hn0[r] = (_Float16)fast_tanh(acc0[r] + (float)xpv0[r]);
                hn1[r] = (_Float16)fast_tanh(acc1[r] + (float)xpv1[r]);
            }
            // own half -> local LDS (fragment layout)
            *(half4v*)&ho[hoff + ebase]       = hn0;
            *(half4v*)&ho[hoff + ebase + 256] = hn1;
            // own half -> L3 exchange blob (same layout, agent-scope bypass)
            __hip_atomic_store((unsigned long long*)hxo + (ebase >> 2),
                               __builtin_bit_cast(unsigned long long, hn0),
                               __ATOMIC_RELAXED, __HIP_MEMORY_SCOPE_AGENT);
            __hip_atomic_store((unsigned long long*)hxo + ((ebase + 256) >> 2),
                               __builtin_bit_cast(unsigned long long, hn1),
                               __ATOMIC_RELAXED, __HIP_MEMORY_SCOPE_AGENT);
            __syncthreads();   // all waves' LDS + hx stores drained (vmcnt 0)
            if (tid == 0)
                __hip_atomic_store(&flags[bid * 16], t, __ATOMIC_RELEASE,
                                   __HIP_MEMORY_SCOPE_AGENT);
        } else {
            float4 o0, o1;
            o0.x = fast_tanh(acc0[0] + (float)xpv0[0]);
            o0.y = fast_tanh(acc0[1] + (float)xpv0[1]);
            o0.z = fast_tanh(acc0[2] + (float)xpv0[2]);
            o0.w = fast_tanh(acc0[3] + (float)xpv0[3]);
            o1.x = fast_tanh(acc1[0] + (float)xpv1[0]);
            o1.y = fast_tanh(acc1[1] + (float)xpv1[1]);
            o1.z = fast_tanh(acc1[2] + (float)xpv1[2]);
            o1.w = fast_tanh(acc1[3] + (float)xpv1[3]);
            float* ob = &out[((size_t)g * 16 + l15) * H + nbase + q * 4];
            *(float4*)&ob[0]  = o0;
            *(float4*)&ob[16] = o1;
        }
    }
}

// ---------------------------------------------------------------------------
extern "C" void kernel_launch(void* const* d_in, const int* in_sizes, int n_in,
                              void* d_out, int out_size, void* d_ws, size_t ws_size,
                              hipStream_t stream)
{
    const float* x   = (const float*)d_in[0];
    const float* Wih = (const float*)d_in[1];
    const float* Whh = (const float*)d_in[2];
    const float* b   = (const float*)d_in[3];
    float* out = (float*)d_out;

    char* ws = (char*)d_ws;
    _Float16* WihT = (_Float16*)(ws + OFF_WIHT);
    _Float16* WhhT = (_Float16*)(ws + OFF_WHHT);
    _Float16* hx   = (_Float16*)(ws + OFF_HX);
    int*      flags = (int*)(ws + OFF_FLAGS);
    _Float16* xp   = (_Float16*)(ws + OFF_XP);

    prep_transpose<<<dim3(16, 16, 2), 256, 0, stream>>>(Wih, Whh, WihT, WhhT, flags);
    xp_gemm<<<dim3(4, 1024), 256, 0, stream>>>(x, WihT, b, xp);
    rnn_scan<<<16, 512, 0, stream>>>(xp, WhhT, out, hx, flags);
}

// Round 2
// 3573.898 us; speedup vs baseline: 1.2563x; 1.0128x over previous
//
#include <hip/hip_runtime.h>
#include <hip/hip_fp16.h>

typedef _Float16 half8 __attribute__((ext_vector_type(8)));
typedef _Float16 half4v __attribute__((ext_vector_type(4)));
typedef float floatx4 __attribute__((ext_vector_type(4)));

constexpr int BN = 128;    // batch
constexpr int T  = 1024;   // time steps
constexpr int D  = 512;    // input dim
constexpr int H  = 512;    // hidden dim

// Workspace layout (bytes)
constexpr size_t OFF_WIHT  = 0;                    // W_ih^T f16 = 512 KB
constexpr size_t OFF_WHHT  = 524288;               // W_hh^T f16 = 512 KB
constexpr size_t OFF_HX    = 1048576;              // h exchange: 2*8*2*4096 f16 = 256 KB
constexpr size_t OFF_FLAGS = 1048576 + 262144;     // 16 flags, 64B stride = 1 KB
constexpr size_t OFF_XP    = 2097152;              // xp f16 [T][B][H] = 128 MB

__device__ __forceinline__ float fast_tanh(float x) {
    float e = __expf(2.0f * x);
    return 1.0f - 2.0f / (e + 1.0f);
}

struct u64x2_s { unsigned long long a, b; };

// ---------------------------------------------------------------------------
// Prep: transpose 512x512 fp32 -> fp16 (row-major [n][k] = W[k][n]).
// Re-arms the scan handshake flags to -1 every launch (stream order
// guarantees completion+visibility before rnn_scan starts).
// ---------------------------------------------------------------------------
__global__ __launch_bounds__(256) void prep_transpose(
    const float* __restrict__ Wih, const float* __restrict__ Whh,
    _Float16* __restrict__ WihT, _Float16* __restrict__ WhhT,
    int* __restrict__ flags)
{
    if (blockIdx.x == 0 && blockIdx.y == 0 && blockIdx.z == 0 && threadIdx.x < 16)
        flags[threadIdx.x * 16] = -1;

    __shared__ float tile[32][33];
    const float* src = (blockIdx.z == 0) ? Wih : Whh;
    _Float16* dst    = (blockIdx.z == 0) ? WihT : WhhT;
    const int tx = threadIdx.x & 31;
    const int ty = threadIdx.x >> 5;
    const int kbase = blockIdx.y * 32;
    const int nbase = blockIdx.x * 32;
    for (int r = 0; r < 4; ++r)
        tile[ty + r * 8][tx] = src[(size_t)(kbase + ty + r * 8) * 512 + nbase + tx];
    __syncthreads();
    for (int r = 0; r < 4; ++r)
        dst[(size_t)(nbase + ty + r * 8) * 512 + kbase + tx] =
            (_Float16)tile[tx][ty + r * 8];
}

// ---------------------------------------------------------------------------
// Phase 1: xp[t][b][n] = x[b][t][:] @ W_ih + bias   (fp16 out, bias folded)
// ---------------------------------------------------------------------------
__global__ __launch_bounds__(256) void xp_gemm(
    const float* __restrict__ x, const _Float16* __restrict__ WT,
    const float* __restrict__ bias, _Float16* __restrict__ xp)
{
    __shared__ _Float16 As[128][40];
    __shared__ _Float16 Bs[128][40];
    const int tid  = threadIdx.x;
    const int lane = tid & 63;
    const int w    = tid >> 6;
    const int wm   = w & 1, wn = w >> 1;
    const int l15  = lane & 15, q = lane >> 4;
    const size_t mbase = (size_t)blockIdx.y * 128;
    const int    nbase = blockIdx.x * 128;

    floatx4 acc[4][4];
    for (int i = 0; i < 4; ++i)
        for (int j = 0; j < 4; ++j)
            acc[i][j] = (floatx4){0.f, 0.f, 0.f, 0.f};

    for (int kt = 0; kt < 16; ++kt) {
        const int k0 = kt * 32;
        {
            const int k4 = (tid & 7) * 4;
            const int row0 = tid >> 3;
            for (int r = 0; r < 4; ++r) {
                const int row = row0 + r * 32;
                const float4 v = *(const float4*)&x[(mbase + row) * D + k0 + k4];
                half4v hv;
                hv[0] = (_Float16)v.x; hv[1] = (_Float16)v.y;
                hv[2] = (_Float16)v.z; hv[3] = (_Float16)v.w;
                *(half4v*)&As[row][k4] = hv;
            }
        }
        {
            const int k8 = (tid & 3) * 8;
            const int n0 = tid >> 2;
            for (int r = 0; r < 2; ++r) {
                const int n = n0 + r * 64;
                *(half8*)&Bs[n][k8] =
                    *(const half8*)&WT[(size_t)(nbase + n) * D + k0 + k8];
            }
        }
        __syncthreads();
        half8 a[4], b[4];
        for (int i = 0; i < 4; ++i)
            a[i] = *(const half8*)&As[wm * 64 + i * 16 + l15][q * 8];
        for (int j = 0; j < 4; ++j)
            b[j] = *(const half8*)&Bs[wn * 64 + j * 16 + l15][q * 8];
        for (int i = 0; i < 4; ++i)
            for (int j = 0; j < 4; ++j)
                acc[i][j] = __builtin_amdgcn_mfma_f32_16x16x32_f16(
                    a[i], b[j], acc[i][j], 0, 0, 0);
        __syncthreads();
    }
    float bc[4];
    for (int j = 0; j < 4; ++j)
        bc[j] = bias[nbase + wn * 64 + j * 16 + l15];
    for (int i = 0; i < 4; ++i)
        for (int r = 0; r < 4; ++r) {
            const size_t row = mbase + wm * 64 + i * 16 + q * 4 + r;
            const int b_row = (int)(row >> 10);      // T = 1024
            const int tt    = (int)(row & 1023);
            _Float16* dst = &xp[((size_t)tt * BN + b_row) * H];
            for (int j = 0; j < 4; ++j) {
                const int col = nbase + wn * 64 + j * 16 + l15;
                dst[col] = (_Float16)(acc[i][j][r] + bc[j]);
            }
        }
}

// ---------------------------------------------------------------------------
// Phase 2: sequential scan, H-split across 16 CUs.
// Block (g, half): 16 batch rows (group g), 256 output cols [half*256, ...).
// W_hh^T slice entirely in AGPRs (8 waves x 128). Per step:
//   - probe peer flag (relaxed, issued at loop top; latency hidden by phase1)
//   - phase 1: own-half k-chunks from LDS (written+barrier'd last step)
//   - confirm flag (retry path only when peer lags), then load the peer's
//     h fragments DIRECTLY into MFMA B-registers from the L3-resident hx
//     blob (sc0|sc1 relaxed atomics: L3 is the serialization point -> no
//     buffer_wbl2 / buffer_inv fences anywhere)
//   - phase 2 MFMAs, tanh, publish own half (hx stores + LDS), one
//     __syncthreads (drains vmcnt), relaxed flag store.
// Ordering: producer = barrier's vmcnt(0) drain before flag; consumer =
// control dep + laundered address dep of data loads on the polled value.
// Lockstep is pairwise self-enforcing; parity double-buffer in hx/LDS.
// ---------------------------------------------------------------------------
__global__ __launch_bounds__(512, 2) void rnn_scan(
    const _Float16* __restrict__ xp, const _Float16* __restrict__ WT,
    float* __restrict__ out, _Float16* __restrict__ hx, int* __restrict__ flags)
{
    __shared__ _Float16 hbuf[2][4096];   // 16 KB: own 256-col half, frag order

    const int bid  = blockIdx.x;        // 0..15
    const int half = bid >> 3;          // output column half
    const int g    = bid & 7;           // batch group
    const int peer16 = (bid ^ 8) * 16;  // partner block's flag slot
    const int bid16  = bid * 16;
    const int tid  = threadIdx.x;
    const int lane = tid & 63;
    const int w    = tid >> 6;          // wave 0..7
    const int l15  = lane & 15;
    const int q    = lane >> 4;

    // W^T rows for this wave's two 16-col m-tiles
    const int nbase = half * 256 + w * 32;
    const _Float16* wr0 = WT + (size_t)(nbase + 0  + l15) * H + q * 8;
    const _Float16* wr1 = WT + (size_t)(nbase + 16 + l15) * H + q * 8;

    // Whole W slice in AGPRs: j=0..7 own-half k-chunks, j=8..15 peer-half
    half8 wa[16][2];
#pragma unroll
    for (int j = 0; j < 16; ++j) {
        const int c = (j < 8) ? (half * 8 + j) : ((half ^ 1) * 8 + (j - 8));
        wa[j][0] = *(const half8*)&wr0[c * 32];
        wa[j][1] = *(const half8*)&wr1[c * 32];
        asm volatile("" : "+a"(wa[j][0]), "+a"(wa[j][1]));
    }

    // own-fragment write base (local to a 4096-elem half-region)
    const int ebase = ((w * 4 + (q >> 1)) * 16 + l15) * 8 + (q & 1) * 4;

    // ---- t = 0: h1(own half) = tanh(xp_0); publish to LDS + hx, flag = 0
    {
        const _Float16* x0 = xp + ((size_t)g * 16 + l15) * H + nbase + q * 4;
        half4v v0 = *(const half4v*)&x0[0];
        half4v v1 = *(const half4v*)&x0[16];
        half4v hn0, hn1;
#pragma unroll
        for (int r = 0; r < 4; ++r) {
            hn0[r] = (_Float16)fast_tanh((float)v0[r]);
            hn1[r] = (_Float16)fast_tanh((float)v1[r]);
        }
        _Float16* hxo = hx + ((size_t)(1 * 8 + g) * 2 + half) * 4096;
        __hip_atomic_store((unsigned long long*)hxo + (ebase >> 2),
                           __builtin_bit_cast(unsigned long long, hn0),
                           __ATOMIC_RELAXED, __HIP_MEMORY_SCOPE_AGENT);
        __hip_atomic_store((unsigned long long*)hxo + ((ebase + 256) >> 2),
                           __builtin_bit_cast(unsigned long long, hn1),
                           __ATOMIC_RELAXED, __HIP_MEMORY_SCOPE_AGENT);
        *(half4v*)&hbuf[1][ebase]       = hn0;
        *(half4v*)&hbuf[1][ebase + 256] = hn1;
        __syncthreads();                 // LDS + vmcnt(0) drain of hx stores
        if (tid == 0)
            __hip_atomic_store(&flags[bid16], 0, __ATOMIC_RELAXED,
                               __HIP_MEMORY_SCOPE_AGENT);
    }

    // lane-fixed xp offset (own 32 cols)
    const _Float16* xlane = xp + ((size_t)g * 16 + l15) * H + nbase + q * 4;
    // lane-fixed offset inside a 1024-ull hx region (frag layout)
    const int poff64 = q * 32 + l15 * 2;

    for (int t = 1; t < T; ++t) {
        // A. early peer-flag probe (latency hides under phase 1)
        int f = __hip_atomic_load(&flags[peer16], __ATOMIC_RELAXED,
                                  __HIP_MEMORY_SCOPE_AGENT);
        __builtin_amdgcn_sched_barrier(0);

        // B. xp prefetch (independent of h)
        const _Float16* xt = xlane + (size_t)t * (BN * H);
        const half4v xpv0 = *(const half4v*)&xt[0];
        const half4v xpv1 = *(const half4v*)&xt[16];

        // C. phase 1: own-half k-chunks from LDS
        const _Float16* hbo = &hbuf[t & 1][(q * 16 + l15) * 8];
        half8 hfA[8];
#pragma unroll
        for (int c8 = 0; c8 < 8; ++c8)
            hfA[c8] = *(const half8*)&hbo[c8 * 512];
        floatx4 acc0 = (floatx4){0.f,0.f,0.f,0.f};
        floatx4 acc1 = (floatx4){0.f,0.f,0.f,0.f};
#pragma unroll
        for (int c8 = 0; c8 < 8; ++c8) {
            acc0 = __builtin_amdgcn_mfma_f32_16x16x32_f16(wa[c8][0], hfA[c8], acc0, 0, 0, 0);
            acc1 = __builtin_amdgcn_mfma_f32_16x16x32_f16(wa[c8][1], hfA[c8], acc1, 0, 0, 0);
        }

        // D. confirm peer published h_t (flag >= t-1); retry only if lagging
        if (f < t - 1) {
            do {
                __builtin_amdgcn_s_sleep(1);
                f = __hip_atomic_load(&flags[peer16], __ATOMIC_RELAXED,
                                      __HIP_MEMORY_SCOPE_AGENT);
            } while (f < t - 1);
        }
        asm volatile("" : "+v"(f));   // launder: keep address dep below alive

        // E. peer fragments straight into MFMA B-regs from L3 (f>>31 == 0)
        const unsigned long long* ps64 = (const unsigned long long*)hx
            + ((size_t)((t & 1) * 8 + g) * 2 + (half ^ 1)) * 1024
            + poff64 + (f >> 31);
        half8 hfB[8];
#pragma unroll
        for (int c8 = 0; c8 < 8; ++c8) {
            unsigned long long d0 = __hip_atomic_load(&ps64[c8 * 128 + 0],
                                    __ATOMIC_RELAXED, __HIP_MEMORY_SCOPE_AGENT);
            unsigned long long d1 = __hip_atomic_load(&ps64[c8 * 128 + 1],
                                    __ATOMIC_RELAXED, __HIP_MEMORY_SCOPE_AGENT);
            hfB[c8] = __builtin_bit_cast(half8, u64x2_s{d0, d1});
        }

        // F. phase 2: peer-half k-chunks
#pragma unroll
        for (int c8 = 0; c8 < 8; ++c8) {
            acc0 = __builtin_amdgcn_mfma_f32_16x16x32_f16(wa[8 + c8][0], hfB[c8], acc0, 0, 0, 0);
            acc1 = __builtin_amdgcn_mfma_f32_16x16x32_f16(wa[8 + c8][1], hfB[c8], acc1, 0, 0, 0);
        }

        // G. tanh + publish
        if (t < T - 1) {
            half4v hn0, hn1;
#pragma unroll
            for (int r = 0; r < 4; ++r) {
                hn0[r] = (_Float16)fast_tanh(acc0[r] + (float)xpv0[r]);
                hn1[r] = (_Float16)fast_tanh(acc1[r] + (float)xpv1[r]);
            }
            _Float16* hxo = hx + ((size_t)(((t + 1) & 1) * 8 + g) * 2 + half) * 4096;
            __hip_atomic_store((unsigned long long*)hxo + (ebase >> 2),
                               __builtin_bit_cast(unsigned long long, hn0),
                               __ATOMIC_RELAXED, __HIP_MEMORY_SCOPE_AGENT);
            __hip_atomic_store((unsigned long long*)hxo + ((ebase + 256) >> 2),
                               __builtin_bit_cast(unsigned long long, hn1),
                               __ATOMIC_RELAXED, __HIP_MEMORY_SCOPE_AGENT);
            _Float16* ho = hbuf[(t + 1) & 1];
            *(half4v*)&ho[ebase]       = hn0;
            *(half4v*)&ho[ebase + 256] = hn1;
            __syncthreads();   // all waves' LDS + hx stores drained (vmcnt 0)
            if (tid == 0)
                __hip_atomic_store(&flags[bid16], t, __ATOMIC_RELAXED,
                                   __HIP_MEMORY_SCOPE_AGENT);
        } else {
            float4 o0, o1;
            o0.x = fast_tanh(acc0[0] + (float)xpv0[0]);
            o0.y = fast_tanh(acc0[1] + (float)xpv0[1]);
            o0.z = fast_tanh(acc0[2] + (float)xpv0[2]);
            o0.w = fast_tanh(acc0[3] + (float)xpv0[3]);
            o1.x = fast_tanh(acc1[0] + (float)xpv1[0]);
            o1.y = fast_tanh(acc1[1] + (float)xpv1[1]);
            o1.z = fast_tanh(acc1[2] + (float)xpv1[2]);
            o1.w = fast_tanh(acc1[3] + (float)xpv1[3]);
            float* ob = &out[((size_t)g * 16 + l15) * H + nbase + q * 4];
            *(float4*)&ob[0]  = o0;
            *(float4*)&ob[16] = o1;
        }
    }
}

// ---------------------------------------------------------------------------
extern "C" void kernel_launch(void* const* d_in, const int* in_sizes, int n_in,
                              void* d_out, int out_size, void* d_ws, size_t ws_size,
                              hipStream_t stream)
{
    const float* x   = (const float*)d_in[0];
    const float* Wih = (const float*)d_in[1];
    const float* Whh = (const float*)d_in[2];
    const float* b   = (const float*)d_in[3];
    float* out = (float*)d_out;

    char* ws = (char*)d_ws;
    _Float16* WihT = (_Float16*)(ws + OFF_WIHT);
    _Float16* WhhT = (_Float16*)(ws + OFF_WHHT);
    _Float16* hx   = (_Float16*)(ws + OFF_HX);
    int*      flags = (int*)(ws + OFF_FLAGS);
    _Float16* xp   = (_Float16*)(ws + OFF_XP);

    prep_transpose<<<dim3(16, 16, 2), 256, 0, stream>>>(Wih, Whh, WihT, WhhT, flags);
    xp_gemm<<<dim3(4, 1024), 256, 0, stream>>>(x, WihT, b, xp);
    rnn_scan<<<16, 512, 0, stream>>>(xp, WhhT, out, hx, flags);
}